// Round 10
// baseline (4354.856 us; speedup 1.0000x reference)
//
#include <hip/hip_runtime.h>
#include <hip/hip_fp16.h>

typedef _Float16 half_t;
typedef __attribute__((ext_vector_type(8))) _Float16 f16x8;
typedef __attribute__((ext_vector_type(4))) float f32x4;

#define DIM   3072
#define NH    24
#define DH    128
#define MLP_D 12288
#define LSEQ  4096
#define BATCH 2
#define NROWS 8192           // B*L
#define N1    21504          // 3*DIM + MLP
#define QKV_N 9216           // 3*DIM
#define CAT_N 15360          // DIM + MLP

__device__ __forceinline__ void gload16(const void* g, void* l) {
  __builtin_amdgcn_global_load_lds((const __attribute__((address_space(1))) void*)g,
                                   (__attribute__((address_space(3))) void*)l, 16, 0, 0);
}

__device__ __forceinline__ float gelu_tanh(float x) {
  float u = 0.7978845608028654f * (x + 0.044715f * x * x * x);
  float t = 1.f - 2.f / (__expf(2.f * u) + 1.f);   // tanh(u)
  return 0.5f * x * (1.f + t);
}

struct EpiParams {
  const float* bias;
  float* outF; int ldoF;
  half_t* o1; int ldo1;   // qkv dest (EPI0)
  half_t* o2; int ldo2;   // concat dest (EPI0 gelu part, EPI2)
  const float* resid;
  const float* gate;      // emb+6144, stride 9216 per batch
  float scale;
};

// ============================================================================
// 256x256 tile, BK=32, 8 waves (2M x 4N; wave tile 128x64).
// KEY CHANGE vs R4-R9 (all ~44% MfmaUtil = LDS-throughput serialization):
// B operand BYPASSES LDS — per-lane direct global->VGPR loads replicating the
// MFMA B-fragment (row = bcol+wc*64+nj*16+(lane&15), kchunk = lane>>4),
// prefetched one K-tile ahead (bfA/bfB ping-pong). LDS carries only A
// (4-deep ring, 16KB slots, global_load_lds DMA). LDS demand drops from
// ~1580 cyc/tile to ~980 < MFMA 1240 -> LDS no longer the binding pipe.
// Plain-C loads => compiler emits fine-grained per-register vmcnt/lgkm waits
// (B(t) wait <= vmcnt(8) provably drains A(t+1) before the end barrier).
// Manual asm only: per-tile end vmcnt(8 | 0 tail) + s_barrier for the A-ring
// cross-wave DMA safety. A-side 16B-chunk XOR swizzle (verified 0-conflict):
// phys = logical ^ ((row>>1)&3), inverse perm on the GLOBAL source (rule 21).
// ============================================================================
template<int EPI>
__global__ __launch_bounds__(512, 2) void gemm256(
    const half_t* __restrict__ A, int lda,
    const half_t* __restrict__ B, int ldb,
    int nbx, int nby, int nsplit, int K, EpiParams ep)
{
  __shared__ __align__(16) char lds[65536];
  const int t = threadIdx.x, lane = t & 63, wid = t >> 6;

  // ---- block swizzle: XCD-contiguous chunks + 8-M-block supertile ----
  const int nwg = nbx * nby;
  const int wg = blockIdx.x;
  const int id = (wg & 7) * (nwg >> 3) + (wg >> 3);   // bijective (nwg%8==0)
  const int panel = 8 * nbx;
  const int bm = (id / panel) * 8 + (id % 8);
  const int bn = (id % panel) / 8;
  const int brow = bm * 256, bcol = bn * 256;
  const int wr = wid >> 2, wc = wid & 3;              // 2 x 4 waves

  f32x4 acc[8][4];
#pragma unroll
  for (int m = 0; m < 8; ++m)
#pragma unroll
    for (int n = 0; n < 4; ++n) acc[m][n] = (f32x4){0.f, 0.f, 0.f, 0.f};

  // ---- A staging (DMA): lane l -> row l>>2 (+16), chunk l&3; source chunk
  // inverse-permuted: src = (l&3) ^ ((l>>3)&3)
  const int scol = (((lane & 3) ^ ((lane >> 3) & 3)) * 8);   // elements
  const half_t* pA = A + (size_t)(brow + wid * 32 + (lane >> 2)) * lda + scol;
  const int NT = K >> 5;

  // ---- A fragment read offsets (swizzled) ----
  const int pc = (((lane >> 4) ^ ((lane >> 1) & 3)) << 4);   // bytes
  const int arow = (wr * 128 + (lane & 15)) * 64 + pc;       // + mi*1024

  // ---- B fragment direct-load pointers (per-lane, exact MFMA layout) ----
  const half_t* pB0 = B + (size_t)(bcol + wc * 64 +  0 + (lane & 15)) * ldb + (lane >> 4) * 8;
  const half_t* pB1 = B + (size_t)(bcol + wc * 64 + 16 + (lane & 15)) * ldb + (lane >> 4) * 8;
  const half_t* pB2 = B + (size_t)(bcol + wc * 64 + 32 + (lane & 15)) * ldb + (lane >> 4) * 8;
  const half_t* pB3 = B + (size_t)(bcol + wc * 64 + 48 + (lane & 15)) * ldb + (lane >> 4) * 8;

  f16x8 bfA[4], bfB[4];

#define STAGE_A(tk) {                                                       \
    char* sb = lds + (((tk) & 3) << 14);                                    \
    const half_t* ga = pA + (size_t)(tk) * 32;                              \
    gload16(ga, sb + wid * 2048);                                           \
    gload16(ga + (size_t)16 * lda, sb + wid * 2048 + 1024); }

#define BODY(tt, BFC, BFN) {                                                \
    char* cb = lds + (((tt) & 3) << 14);                                    \
    f16x8 af[8];                                                            \
    af[0] = *(const f16x8*)(cb + arow);                                     \
    af[1] = *(const f16x8*)(cb + arow + 1024);                              \
    af[2] = *(const f16x8*)(cb + arow + 2048);                              \
    af[3] = *(const f16x8*)(cb + arow + 3072);                              \
    af[4] = *(const f16x8*)(cb + arow + 4096);                              \
    af[5] = *(const f16x8*)(cb + arow + 5120);                              \
    af[6] = *(const f16x8*)(cb + arow + 6144);                              \
    af[7] = *(const f16x8*)(cb + arow + 7168);                              \
    if ((tt) + 1 < NT) {                                                    \
      BFN[0] = *(const f16x8*)(pB0 + (size_t)((tt) + 1) * 32);              \
      BFN[1] = *(const f16x8*)(pB1 + (size_t)((tt) + 1) * 32);              \
      BFN[2] = *(const f16x8*)(pB2 + (size_t)((tt) + 1) * 32);              \
      BFN[3] = *(const f16x8*)(pB3 + (size_t)((tt) + 1) * 32);              \
    }                                                                       \
    if ((tt) + 3 < NT) STAGE_A((tt) + 3)                                    \
    __builtin_amdgcn_s_setprio(1);                                          \
    _Pragma("unroll")                                                       \
    for (int mi = 0; mi < 8; ++mi)                                          \
      _Pragma("unroll")                                                     \
      for (int nj = 0; nj < 4; ++nj)                                        \
        acc[mi][nj] = __builtin_amdgcn_mfma_f32_16x16x32_f16(               \
            af[mi], BFC[nj], acc[mi][nj], 0, 0, 0);                         \
    __builtin_amdgcn_s_setprio(0);                                          \
    __builtin_amdgcn_sched_barrier(0);                                      \
    if ((tt) + 3 < NT) asm volatile("s_waitcnt vmcnt(8)" ::: "memory");     \
    else               asm volatile("s_waitcnt vmcnt(0)" ::: "memory");     \
    __builtin_amdgcn_s_barrier();                                           \
    asm volatile("" ::: "memory"); }

  // ---- prologue: stage A tiles 0..2; load B(0); full drain; barrier ----
  STAGE_A(0) STAGE_A(1) STAGE_A(2)
  bfA[0] = *(const f16x8*)(pB0);
  bfA[1] = *(const f16x8*)(pB1);
  bfA[2] = *(const f16x8*)(pB2);
  bfA[3] = *(const f16x8*)(pB3);
  asm volatile("s_waitcnt vmcnt(0)" ::: "memory");
  __builtin_amdgcn_s_barrier();
  asm volatile("" ::: "memory");

  for (int tt = 0; tt < NT; tt += 2) {   // NT even for all our K
    BODY(tt, bfA, bfB)
    BODY(tt + 1, bfB, bfA)
  }
#undef STAGE_A
#undef BODY

  // ---- epilogue ----
  const int laneR = lane & 15;
  const int colb = bcol + wc * 64;
  const int rowb = brow + wr * 128 + (lane >> 4) * 4;
#pragma unroll
  for (int mi = 0; mi < 8; ++mi) {
#pragma unroll
    for (int nj = 0; nj < 4; ++nj) {
      int col = colb + nj * 16 + laneR;
#pragma unroll
      for (int j = 0; j < 4; ++j) {
        int row = rowb + mi * 16 + j;
        float v = acc[mi][nj][j];
        if (EPI == 0) {
          v += ep.bias[col];
          if (col < nsplit) {
            ep.o1[(size_t)row * ep.ldo1 + col] = (half_t)v;
          } else {
            ep.o2[(size_t)row * ep.ldo2 + DIM + (col - nsplit)] = (half_t)gelu_tanh(v);
          }
        } else if (EPI == 1) {
          ep.outF[(size_t)row * ep.ldoF + col] = v * ep.scale;
        } else if (EPI == 2) {
          ep.o2[(size_t)row * ep.ldo2 + col] = (half_t)v;
        } else {
          v += ep.bias[col];
          int b = row >> 12;
          float g = ep.gate[(size_t)b * QKV_N + col];
          float r = ep.resid[(size_t)row * DIM + col];
          ep.outF[(size_t)row * ep.ldoF + col] = r + g * v;
        }
      }
    }
  }
}

// emb = silu(temb) @ w_lin + b_lin   (2 x 9216)
__global__ __launch_bounds__(256) void k_emb(
    const float* __restrict__ temb, const float* __restrict__ w_lin,
    const float* __restrict__ b_lin, float* __restrict__ emb)
{
  __shared__ float s[DIM];
  int b = blockIdx.y;
  int col = blockIdx.x * 256 + threadIdx.x;
  const float* tr = temb + (size_t)b * DIM;
  for (int k = threadIdx.x; k < DIM; k += 256) {
    float x = tr[k];
    s[k] = x / (1.f + __expf(-x));
  }
  __syncthreads();
  float acc = b_lin[col];
  for (int k = 0; k < DIM; k += 4) {
    acc += s[k] * w_lin[(size_t)k * QKV_N + col]
         + s[k + 1] * w_lin[(size_t)(k + 1) * QKV_N + col]
         + s[k + 2] * w_lin[(size_t)(k + 2) * QKV_N + col]
         + s[k + 3] * w_lin[(size_t)(k + 3) * QKV_N + col];
  }
  emb[(size_t)b * QKV_N + col] = acc;
}

// LayerNorm + (1+scale)*xhat + shift -> fp16
__global__ __launch_bounds__(256) void k_lnmod(
    const float* __restrict__ hs, const float* __restrict__ emb,
    half_t* __restrict__ xmod)
{
  int row = blockIdx.x;
  int b = row >> 12;
  const float* x = hs + (size_t)row * DIM;
  int t = threadIdx.x;
  float s = 0.f, s2 = 0.f;
  float4 v[3];
#pragma unroll
  for (int i = 0; i < 3; ++i) {
    v[i] = ((const float4*)x)[t + 256 * i];
    s  += v[i].x + v[i].y + v[i].z + v[i].w;
    s2 += v[i].x * v[i].x + v[i].y * v[i].y + v[i].z * v[i].z + v[i].w * v[i].w;
  }
  for (int o = 32; o; o >>= 1) { s += __shfl_xor(s, o); s2 += __shfl_xor(s2, o); }
  __shared__ float rs[4], rs2[4];
  int lane = t & 63, w = t >> 6;
  if (lane == 0) { rs[w] = s; rs2[w] = s2; }
  __syncthreads();
  s = rs[0] + rs[1] + rs[2] + rs[3];
  s2 = rs2[0] + rs2[1] + rs2[2] + rs2[3];
  float mu = s * (1.f / DIM);
  float var = s2 * (1.f / DIM) - mu * mu;
  float rstd = rsqrtf(var + 1e-6f);
  const float* shift = emb + (size_t)b * QKV_N;
  const float* scale = shift + DIM;
#pragma unroll
  for (int i = 0; i < 3; ++i) {
    int g = t + 256 * i;
    float4 sc = ((const float4*)scale)[g];
    float4 sh = ((const float4*)shift)[g];
    half_t ob[4];
    float vv[4] = {v[i].x, v[i].y, v[i].z, v[i].w};
    float scv[4] = {sc.x, sc.y, sc.z, sc.w};
    float shv[4] = {sh.x, sh.y, sh.z, sh.w};
#pragma unroll
    for (int j = 0; j < 4; ++j) {
      float xn = (vv[j] - mu) * rstd;
      ob[j] = (half_t)(xn * (1.f + scv[j]) + shv[j]);
    }
    *(uint2*)&xmod[(size_t)row * DIM + g * 4] = *(uint2*)ob;
  }
}

// f32 (RxC) -> fp16 transposed (CxR)
__global__ __launch_bounds__(256) void k_transpose_cvt(
    const float* __restrict__ in, half_t* __restrict__ out, int R, int C)
{
  __shared__ float s[64][65];
  int c0 = blockIdx.x * 64, r0 = blockIdx.y * 64;
  int tx = threadIdx.x & 63, ty = threadIdx.x >> 6;
#pragma unroll
  for (int j = 0; j < 16; ++j) {
    int r = ty + j * 4;
    s[r][tx] = in[(size_t)(r0 + r) * C + c0 + tx];
  }
  __syncthreads();
#pragma unroll
  for (int j = 0; j < 16; ++j) {
    int c = ty + j * 4;
    out[(size_t)(c0 + c) * R + r0 + tx] = (half_t)s[tx][c];
  }
}

// RMS + RoPE on q,k in-place in qkv buffer. One wave per (row, head, q/k).
__global__ __launch_bounds__(256) void k_qk_rmsrope(
    half_t* __restrict__ qkv, const float* __restrict__ rope,
    const float* __restrict__ q_scale, const float* __restrict__ k_scale)
{
  int w = blockIdx.x * 4 + (threadIdx.x >> 6);
  int lane = threadIdx.x & 63;
  int qk = w & 1;
  int hr = w >> 1;               // bl*24 + h
  int h = hr % 24;
  int bl = hr / 24;              // b*4096 + l
  size_t base = (size_t)bl * QKV_N + qk * DIM + h * DH;
  float x0 = (float)qkv[base + lane * 2];
  float x1 = (float)qkv[base + lane * 2 + 1];
  float ss = x0 * x0 + x1 * x1;
  for (int o = 32; o; o >>= 1) ss += __shfl_xor(ss, o);
  float r = rsqrtf(ss * (1.f / DH) + 1e-6f);
  const float* sc = qk ? k_scale : q_scale;
  float xs0 = x0 * r * sc[lane * 2];
  float xs1 = x1 * r * sc[lane * 2 + 1];
  int l = bl & (LSEQ - 1);
  float4 fr = ((const float4*)rope)[(size_t)l * 64 + lane];
  qkv[base + lane * 2]     = (half_t)(fr.x * xs0 + fr.y * xs1);
  qkv[base + lane * 2 + 1] = (half_t)(fr.z * xs0 + fr.w * xs1);
}

// v part of qkv -> vT (per batch: DIM x LSEQ), tiled transpose
__global__ __launch_bounds__(256) void k_vT(
    const half_t* __restrict__ qkv, half_t* __restrict__ vT)
{
  __shared__ half_t s[64][65];
  int b = blockIdx.z;
  int l0 = blockIdx.x * 64, d0 = blockIdx.y * 64;
  int tx = threadIdx.x & 63, ty = threadIdx.x >> 6;
#pragma unroll
  for (int j = 0; j < 16; ++j) {
    int l = ty + j * 4;
    s[l][tx] = qkv[(size_t)(b * LSEQ + l0 + l) * QKV_N + 2 * DIM + d0 + tx];
  }
  __syncthreads();
#pragma unroll
  for (int j = 0; j < 16; ++j) {
    int d = ty + j * 4;
    vT[((size_t)b * DIM + d0 + d) * LSEQ + l0 + tx] = s[tx][d];
  }
}

// row softmax: S (4096 f32) -> P fp16
__global__ __launch_bounds__(256) void k_softmax(
    const float* __restrict__ S, half_t* __restrict__ P)
{
  int row = blockIdx.x;
  const float* srow = S + (size_t)row * LSEQ;
  int t = threadIdx.x;
  float4 v[4];
  float mx = -1e30f;
#pragma unroll
  for (int i = 0; i < 4; ++i) {
    v[i] = ((const float4*)srow)[t + 256 * i];
    mx = fmaxf(mx, fmaxf(fmaxf(v[i].x, v[i].y), fmaxf(v[i].z, v[i].w)));
  }
  for (int o = 32; o; o >>= 1) mx = fmaxf(mx, __shfl_xor(mx, o));
  __shared__ float rmx[4], rsum[4];
  int lane = t & 63, w = t >> 6;
  if (lane == 0) rmx[w] = mx;
  __syncthreads();
  mx = fmaxf(fmaxf(rmx[0], rmx[1]), fmaxf(rmx[2], rmx[3]));
  float s = 0.f;
#pragma unroll
  for (int i = 0; i < 4; ++i) {
    v[i].x = __expf(v[i].x - mx); v[i].y = __expf(v[i].y - mx);
    v[i].z = __expf(v[i].z - mx); v[i].w = __expf(v[i].w - mx);
    s += v[i].x + v[i].y + v[i].z + v[i].w;
  }
  for (int o = 32; o; o >>= 1) s += __shfl_xor(s, o);
  if (lane == 0) rsum[w] = s;
  __syncthreads();
  s = rsum[0] + rsum[1] + rsum[2] + rsum[3];
  float inv = 1.f / s;
#pragma unroll
  for (int i = 0; i < 4; ++i) {
    half_t ob[4] = {
      (half_t)(v[i].x * inv), (half_t)(v[i].y * inv),
      (half_t)(v[i].z * inv), (half_t)(v[i].w * inv)};
    *(uint2*)&P[(size_t)row * LSEQ + (t + 256 * i) * 4] = *(uint2*)ob;
  }
}

extern "C" void kernel_launch(void* const* d_in, const int* in_sizes, int n_in,
                              void* d_out, int out_size, void* d_ws, size_t ws_size,
                              hipStream_t stream) {
  const float* hs      = (const float*)d_in[0];
  const float* temb    = (const float*)d_in[1];
  const float* rope    = (const float*)d_in[2];
  const float* w_lin   = (const float*)d_in[3];
  const float* b_lin   = (const float*)d_in[4];
  const float* w1      = (const float*)d_in[5];
  const float* b1      = (const float*)d_in[6];
  const float* w2      = (const float*)d_in[7];
  const float* b2      = (const float*)d_in[8];
  const float* q_scale = (const float*)d_in[9];
  const float* k_scale = (const float*)d_in[10];
  float* out = (float*)d_out;

  char* ws = (char*)d_ws;
  size_t off = 0;
  auto alloc = [&](size_t bytes) { char* p = ws + off; off += (bytes + 255) & ~(size_t)255; return p; };
  float*  emb    = (float*) alloc((size_t)BATCH * QKV_N * 4);
  half_t* xmod   = (half_t*)alloc((size_t)NROWS * DIM * 2);
  half_t* w1T    = (half_t*)alloc((size_t)N1 * DIM * 2);
  half_t* w2T    = (half_t*)alloc((size_t)DIM * CAT_N * 2);
  half_t* qkv    = (half_t*)alloc((size_t)NROWS * QKV_N * 2);
  half_t* concat = (half_t*)alloc((size_t)NROWS * CAT_N * 2);
  half_t* vT     = (half_t*)alloc((size_t)BATCH * DIM * LSEQ * 2);
  float*  Sbuf   = (float*) alloc((size_t)LSEQ * LSEQ * 4);
  half_t* Pbuf   = (half_t*)alloc((size_t)LSEQ * LSEQ * 2);
  (void)ws_size; (void)n_in; (void)in_sizes; (void)out_size;

  k_emb<<<dim3(QKV_N / 256, BATCH), 256, 0, stream>>>(temb, w_lin, b_lin, emb);
  k_transpose_cvt<<<dim3(N1 / 64, DIM / 64), 256, 0, stream>>>(w1, w1T, DIM, N1);
  k_transpose_cvt<<<dim3(DIM / 64, CAT_N / 64), 256, 0, stream>>>(w2, w2T, CAT_N, DIM);
  k_lnmod<<<NROWS, 256, 0, stream>>>(hs, emb, xmod);

  // GEMM1: proj = xmod @ w1 + b1 ; qkv part -> qkv buf, mlp part -> gelu -> concat[:,3072:]
  EpiParams ep1 = {b1, nullptr, 0, qkv, QKV_N, concat, CAT_N, nullptr, nullptr, 0.f};
  gemm256<0><<<(N1 / 256) * (NROWS / 256), 512, 0, stream>>>(
      xmod, DIM, w1T, DIM, N1 / 256, NROWS / 256, QKV_N, DIM, ep1);

  k_qk_rmsrope<<<(NROWS * NH * 2) / 4, 256, 0, stream>>>(qkv, rope, q_scale, k_scale);
  k_vT<<<dim3(LSEQ / 64, DIM / 64, BATCH), 256, 0, stream>>>(qkv, vT);

  for (int b = 0; b < BATCH; ++b) {
    const half_t* qb = qkv + (size_t)b * LSEQ * QKV_N;
    EpiParams epS = {nullptr, Sbuf, LSEQ, nullptr, 0, nullptr, 0, nullptr, nullptr, 0.08838834764831845f};
    gemm256<1><<<(LSEQ / 256) * (LSEQ / 256), 512, 0, stream>>>(
        qb, QKV_N, qb + DIM, QKV_N, LSEQ / 256, LSEQ / 256, 0, DIM, epS);
    k_softmax<<<LSEQ, 256, 0, stream>>>(Sbuf, Pbuf);
    EpiParams epPV = {nullptr, nullptr, 0, nullptr, 0,
                      concat + (size_t)b * LSEQ * CAT_N, CAT_N, nullptr, nullptr, 0.f};
    gemm256<2><<<(DIM / 256) * (LSEQ / 256), 512, 0, stream>>>(
        Pbuf, LSEQ, vT + (size_t)b * DIM * LSEQ, LSEQ, DIM / 256, LSEQ / 256, 0, LSEQ, epPV);
  }

  // GEMM2: out = resid + gate * (concat @ w2 + b2)
  EpiParams ep2 = {b2, out, DIM, nullptr, 0, nullptr, 0, hs, emb + 2 * DIM, 0.f};
  gemm256<3><<<(DIM / 256) * (NROWS / 256), 512, 0, stream>>>(
      concat, CAT_N, w2T, CAT_N, DIM / 256, NROWS / 256, 0, CAT_N, ep2);
}

// Round 11
// 2798.388 us; speedup vs baseline: 1.5562x; 1.5562x over previous
//
#include <hip/hip_runtime.h>
#include <hip/hip_fp16.h>

typedef _Float16 half_t;
typedef __attribute__((ext_vector_type(8))) _Float16 f16x8;
typedef __attribute__((ext_vector_type(4))) float f32x4;

#define DIM   3072
#define NH    24
#define DH    128
#define MLP_D 12288
#define LSEQ  4096
#define BATCH 2
#define NROWS 8192           // B*L
#define N1    21504          // 3*DIM + MLP
#define QKV_N 9216           // 3*DIM
#define CAT_N 15360          // DIM + MLP

__device__ __forceinline__ void gload16(const void* g, void* l) {
  __builtin_amdgcn_global_load_lds((const __attribute__((address_space(1))) void*)g,
                                   (__attribute__((address_space(3))) void*)l, 16, 0, 0);
}

__device__ __forceinline__ float gelu_tanh(float x) {
  float u = 0.7978845608028654f * (x + 0.044715f * x * x * x);
  float t = 1.f - 2.f / (__expf(2.f * u) + 1.f);   // tanh(u)
  return 0.5f * x * (1.f + t);
}

struct EpiParams {
  const float* bias;
  float* outF; int ldoF;
  half_t* o1; int ldo1;   // qkv dest (EPI0) / S dest fp16 (EPI1)
  half_t* o2; int ldo2;   // concat dest (EPI0 gelu part, EPI2)
  const float* resid;
  const float* gate;      // emb+6144, stride 9216 per batch
  float scale;
};

// ============================================================================
// R6 structure (best measured: gemm<0> 1151us, MfmaUtil 44%, 0 conflicts).
// 256x256 tile, BK=64, 8 waves (2M x 4N). READ-AHEAD phase pipeline:
// per phase: lgkm(0) [reads issued a full phase ago] -> MFMA quadrant ->
// issue NEXT quadrant's ds_reads (af/bf reg double-buffer) -> stage exactly
// 1 half-tile -> s_barrier. vmcnt(6) once per tile at P2; vmcnt(0) tail only.
// LDS per buffer: A[2kh][256r][32c] @0, B @32768. 16B-chunk XOR swizzle
// phys=logical^((row>>1)&3), inverse perm on the GLOBAL source (rule #21).
// EPI1 writes S as fp16 (saves half the S HBM traffic; |S|<=~40 -> abs err
// <=0.02, inside absmax headroom).
// ============================================================================
template<int EPI>
__global__ __launch_bounds__(512, 2) void gemm256(
    const half_t* __restrict__ A, int lda,
    const half_t* __restrict__ B, int ldb,
    int nbx, int nby, int nsplit, int K, EpiParams ep)
{
  __shared__ __align__(16) char lds[131072];
  const int t = threadIdx.x, lane = t & 63, wid = t >> 6;

  // ---- block swizzle: XCD-contiguous chunks + 8-M-block supertile ----
  const int nwg = nbx * nby;
  const int wg = blockIdx.x;
  const int id = (wg & 7) * (nwg >> 3) + (wg >> 3);   // bijective (nwg%8==0)
  const int panel = 8 * nbx;
  const int bm = (id / panel) * 8 + (id % 8);
  const int bn = (id % panel) / 8;
  const int brow = bm * 256, bcol = bn * 256;
  const int wr = wid >> 2, wc = wid & 3;              // 2 x 4 waves

  f32x4 acc[8][4];
#pragma unroll
  for (int m = 0; m < 8; ++m)
#pragma unroll
    for (int n = 0; n < 4; ++n) acc[m][n] = (f32x4){0.f, 0.f, 0.f, 0.f};

  // ---- staging pointers: lane l -> row (l>>2)[+16], chunk (l&3); source
  // chunk inverse-permuted so LDS holds phys = logical ^ ((row>>1)&3)
  const int scol = (((lane & 3) ^ ((lane >> 3) & 3)) * 8);   // halves
  const half_t* pA = A + (size_t)(brow + wid * 32 + (lane >> 2)) * lda + scol;
  const half_t* pB = B + (size_t)(bcol + wid * 32 + (lane >> 2)) * ldb + scol;
  const int wrow = wid * 2048;          // byte offset of this wave's 32 rows
  const int NT = K >> 6;

  // ---- fragment read offsets (swizzled chunk) ----
  const int pc = (((lane >> 4) ^ ((lane >> 1) & 3)) << 4);   // bytes
  const int aoff = (wr * 128 + (lane & 15)) * 64 + pc;
  const int boff = 32768 + (wc * 64 + (lane & 15)) * 64 + pc;

  f16x8 af[2][4], bf[2][4];

#define STAGE_A(bb, kh, tk) {                                               \
    gload16(pA + (size_t)(tk) * 64 + (kh) * 32,                             \
            (bb) + (kh) * 16384 + wrow);                                    \
    gload16(pA + (size_t)(tk) * 64 + (kh) * 32 + (size_t)16 * lda,          \
            (bb) + (kh) * 16384 + wrow + 1024); }
#define STAGE_B(bb, kh, tk) {                                               \
    gload16(pB + (size_t)(tk) * 64 + (kh) * 32,                             \
            (bb) + 32768 + (kh) * 16384 + wrow);                            \
    gload16(pB + (size_t)(tk) * 64 + (kh) * 32 + (size_t)16 * ldb,          \
            (bb) + 32768 + (kh) * 16384 + wrow + 1024); }

#define MFMA_Q(accoff, ab, bb2)                                             \
    _Pragma("unroll")                                                       \
    for (int mi = 0; mi < 4; ++mi)                                          \
      _Pragma("unroll")                                                     \
      for (int nj = 0; nj < 4; ++nj)                                        \
        acc[(accoff) + mi][nj] = __builtin_amdgcn_mfma_f32_16x16x32_f16(    \
            af[ab][mi], bf[bb2][nj], acc[(accoff) + mi][nj], 0, 0, 0);

#define PHASE_HEAD                                                          \
    asm volatile("s_waitcnt lgkmcnt(0)" ::: "memory");                      \
    __builtin_amdgcn_sched_barrier(0);                                      \
    __builtin_amdgcn_s_setprio(1);

#define PHASE_MID                                                           \
    __builtin_amdgcn_s_setprio(0);                                          \
    __builtin_amdgcn_sched_barrier(0);

  // ---- prologue: stage tiles 0 and 1; pre-read Q0 fragments of tile 0 ----
  {
    char* b0 = lds;
    char* b1 = lds + 65536;
    STAGE_B(b0, 0, 0); STAGE_A(b0, 0, 0); STAGE_B(b0, 1, 0); STAGE_A(b0, 1, 0);
    STAGE_B(b1, 0, 1); STAGE_A(b1, 0, 1); STAGE_B(b1, 1, 1); STAGE_A(b1, 1, 1);
    asm volatile("s_waitcnt vmcnt(8)" ::: "memory");   // tile 0 landed
    __builtin_amdgcn_s_barrier();
#pragma unroll
    for (int mi = 0; mi < 4; ++mi) af[0][mi] = *(const f16x8*)(lds + aoff + mi * 1024);
#pragma unroll
    for (int nj = 0; nj < 4; ++nj) bf[0][nj] = *(const f16x8*)(lds + boff + nj * 1024);
    __builtin_amdgcn_sched_barrier(0);
    __builtin_amdgcn_s_barrier();      // all waves issued pre-reads
  }

  for (int tt = 0; tt < NT; ++tt) {
    char* cb = lds + (size_t)(tt & 1) * 65536;
    char* nb = lds + (size_t)((tt & 1) ^ 1) * 65536;

    // ===== P0: MFMA Q0 (kk0,mh0); read af[1] <- A kh0 mh1; stage B kh0 =====
    PHASE_HEAD
    MFMA_Q(0, 0, 0)
    PHASE_MID
#pragma unroll
    for (int mi = 0; mi < 4; ++mi) af[1][mi] = *(const f16x8*)(cb + aoff + 4096 + mi * 1024);
    if (tt + 2 < NT) STAGE_B(cb, 0, tt + 2);
    __builtin_amdgcn_sched_barrier(0);
    __builtin_amdgcn_s_barrier();

    // ===== P1: MFMA Q1 (kk0,mh1) w/ bf0; read af[0] <- A kh1 mh0, bf[1] <- B kh1;
    //           stage A kh0 =====
    PHASE_HEAD
    MFMA_Q(4, 1, 0)
    PHASE_MID
#pragma unroll
    for (int mi = 0; mi < 4; ++mi) af[0][mi] = *(const f16x8*)(cb + aoff + 16384 + mi * 1024);
#pragma unroll
    for (int nj = 0; nj < 4; ++nj) bf[1][nj] = *(const f16x8*)(cb + boff + 16384 + nj * 1024);
    if (tt + 2 < NT) STAGE_A(cb, 0, tt + 2);
    __builtin_amdgcn_sched_barrier(0);
    __builtin_amdgcn_s_barrier();

    // ===== P2: MFMA Q2 (kk1,mh0) w/ bf1; read af[1] <- A kh1 mh1; stage B kh1;
    //           vmcnt gate for next-buffer reads =====
    PHASE_HEAD
    MFMA_Q(0, 0, 1)
    PHASE_MID
#pragma unroll
    for (int mi = 0; mi < 4; ++mi) af[1][mi] = *(const f16x8*)(cb + aoff + 16384 + 4096 + mi * 1024);
    if (tt + 2 < NT) STAGE_B(cb, 1, tt + 2);
    __builtin_amdgcn_sched_barrier(0);
    if (tt + 2 < NT) asm volatile("s_waitcnt vmcnt(6)" ::: "memory");
    else             asm volatile("s_waitcnt vmcnt(0)" ::: "memory");
    __builtin_amdgcn_s_barrier();

    // ===== P3: MFMA Q3 (kk1,mh1) w/ bf1; read next tile's Q0 frags from nb;
    //           stage A kh1 =====
    PHASE_HEAD
    MFMA_Q(4, 1, 1)
    PHASE_MID
    if (tt + 1 < NT) {
#pragma unroll
      for (int mi = 0; mi < 4; ++mi) af[0][mi] = *(const f16x8*)(nb + aoff + mi * 1024);
#pragma unroll
      for (int nj = 0; nj < 4; ++nj) bf[0][nj] = *(const f16x8*)(nb + boff + nj * 1024);
    }
    if (tt + 2 < NT) STAGE_A(cb, 1, tt + 2);
    __builtin_amdgcn_sched_barrier(0);
    __builtin_amdgcn_s_barrier();
  }
#undef STAGE_A
#undef STAGE_B
#undef MFMA_Q
#undef PHASE_HEAD
#undef PHASE_MID

  // ---- epilogue ----
  const int laneR = lane & 15;
  const int colb = bcol + wc * 64;
  const int rowb = brow + wr * 128 + (lane >> 4) * 4;
#pragma unroll
  for (int mi = 0; mi < 8; ++mi) {
#pragma unroll
    for (int nj = 0; nj < 4; ++nj) {
      int col = colb + nj * 16 + laneR;
#pragma unroll
      for (int j = 0; j < 4; ++j) {
        int row = rowb + mi * 16 + j;
        float v = acc[mi][nj][j];
        if (EPI == 0) {
          v += ep.bias[col];
          if (col < nsplit) {
            ep.o1[(size_t)row * ep.ldo1 + col] = (half_t)v;
          } else {
            ep.o2[(size_t)row * ep.ldo2 + DIM + (col - nsplit)] = (half_t)gelu_tanh(v);
          }
        } else if (EPI == 1) {
          ep.o1[(size_t)row * ep.ldo1 + col] = (half_t)(v * ep.scale);
        } else if (EPI == 2) {
          ep.o2[(size_t)row * ep.ldo2 + col] = (half_t)v;
        } else {
          v += ep.bias[col];
          int b = row >> 12;
          float g = ep.gate[(size_t)b * QKV_N + col];
          float r = ep.resid[(size_t)row * DIM + col];
          ep.outF[(size_t)row * ep.ldoF + col] = r + g * v;
        }
      }
    }
  }
}

// emb = silu(temb) @ w_lin + b_lin   (2 x 9216)
__global__ __launch_bounds__(256) void k_emb(
    const float* __restrict__ temb, const float* __restrict__ w_lin,
    const float* __restrict__ b_lin, float* __restrict__ emb)
{
  __shared__ float s[DIM];
  int b = blockIdx.y;
  int col = blockIdx.x * 256 + threadIdx.x;
  const float* tr = temb + (size_t)b * DIM;
  for (int k = threadIdx.x; k < DIM; k += 256) {
    float x = tr[k];
    s[k] = x / (1.f + __expf(-x));
  }
  __syncthreads();
  float acc = b_lin[col];
  for (int k = 0; k < DIM; k += 4) {
    acc += s[k] * w_lin[(size_t)k * QKV_N + col]
         + s[k + 1] * w_lin[(size_t)(k + 1) * QKV_N + col]
         + s[k + 2] * w_lin[(size_t)(k + 2) * QKV_N + col]
         + s[k + 3] * w_lin[(size_t)(k + 3) * QKV_N + col];
  }
  emb[(size_t)b * QKV_N + col] = acc;
}

// LayerNorm + (1+scale)*xhat + shift -> fp16
__global__ __launch_bounds__(256) void k_lnmod(
    const float* __restrict__ hs, const float* __restrict__ emb,
    half_t* __restrict__ xmod)
{
  int row = blockIdx.x;
  int b = row >> 12;
  const float* x = hs + (size_t)row * DIM;
  int t = threadIdx.x;
  float s = 0.f, s2 = 0.f;
  float4 v[3];
#pragma unroll
  for (int i = 0; i < 3; ++i) {
    v[i] = ((const float4*)x)[t + 256 * i];
    s  += v[i].x + v[i].y + v[i].z + v[i].w;
    s2 += v[i].x * v[i].x + v[i].y * v[i].y + v[i].z * v[i].z + v[i].w * v[i].w;
  }
  for (int o = 32; o; o >>= 1) { s += __shfl_xor(s, o); s2 += __shfl_xor(s2, o); }
  __shared__ float rs[4], rs2[4];
  int lane = t & 63, w = t >> 6;
  if (lane == 0) { rs[w] = s; rs2[w] = s2; }
  __syncthreads();
  s = rs[0] + rs[1] + rs[2] + rs[3];
  s2 = rs2[0] + rs2[1] + rs2[2] + rs2[3];
  float mu = s * (1.f / DIM);
  float var = s2 * (1.f / DIM) - mu * mu;
  float rstd = rsqrtf(var + 1e-6f);
  const float* shift = emb + (size_t)b * QKV_N;
  const float* scale = shift + DIM;
#pragma unroll
  for (int i = 0; i < 3; ++i) {
    int g = t + 256 * i;
    float4 sc = ((const float4*)scale)[g];
    float4 sh = ((const float4*)shift)[g];
    half_t ob[4];
    float vv[4] = {v[i].x, v[i].y, v[i].z, v[i].w};
    float scv[4] = {sc.x, sc.y, sc.z, sc.w};
    float shv[4] = {sh.x, sh.y, sh.z, sh.w};
#pragma unroll
    for (int j = 0; j < 4; ++j) {
      float xn = (vv[j] - mu) * rstd;
      ob[j] = (half_t)(xn * (1.f + scv[j]) + shv[j]);
    }
    *(uint2*)&xmod[(size_t)row * DIM + g * 4] = *(uint2*)ob;
  }
}

// f32 (RxC) -> fp16 transposed (CxR)
__global__ __launch_bounds__(256) void k_transpose_cvt(
    const float* __restrict__ in, half_t* __restrict__ out, int R, int C)
{
  __shared__ float s[64][65];
  int c0 = blockIdx.x * 64, r0 = blockIdx.y * 64;
  int tx = threadIdx.x & 63, ty = threadIdx.x >> 6;
#pragma unroll
  for (int j = 0; j < 16; ++j) {
    int r = ty + j * 4;
    s[r][tx] = in[(size_t)(r0 + r) * C + c0 + tx];
  }
  __syncthreads();
#pragma unroll
  for (int j = 0; j < 16; ++j) {
    int c = ty + j * 4;
    out[(size_t)(c0 + c) * R + r0 + tx] = (half_t)s[tx][c];
  }
}

// RMS + RoPE on q,k in-place in qkv buffer. One wave per (row, head, q/k).
__global__ __launch_bounds__(256) void k_qk_rmsrope(
    half_t* __restrict__ qkv, const float* __restrict__ rope,
    const float* __restrict__ q_scale, const float* __restrict__ k_scale)
{
  int w = blockIdx.x * 4 + (threadIdx.x >> 6);
  int lane = threadIdx.x & 63;
  int qk = w & 1;
  int hr = w >> 1;               // bl*24 + h
  int h = hr % 24;
  int bl = hr / 24;              // b*4096 + l
  size_t base = (size_t)bl * QKV_N + qk * DIM + h * DH;
  float x0 = (float)qkv[base + lane * 2];
  float x1 = (float)qkv[base + lane * 2 + 1];
  float ss = x0 * x0 + x1 * x1;
  for (int o = 32; o; o >>= 1) ss += __shfl_xor(ss, o);
  float r = rsqrtf(ss * (1.f / DH) + 1e-6f);
  const float* sc = qk ? k_scale : q_scale;
  float xs0 = x0 * r * sc[lane * 2];
  float xs1 = x1 * r * sc[lane * 2 + 1];
  int l = bl & (LSEQ - 1);
  float4 fr = ((const float4*)rope)[(size_t)l * 64 + lane];
  qkv[base + lane * 2]     = (half_t)(fr.x * xs0 + fr.y * xs1);
  qkv[base + lane * 2 + 1] = (half_t)(fr.z * xs0 + fr.w * xs1);
}

// v part of qkv -> vT (per batch: DIM x LSEQ), tiled transpose
__global__ __launch_bounds__(256) void k_vT(
    const half_t* __restrict__ qkv, half_t* __restrict__ vT)
{
  __shared__ half_t s[64][65];
  int b = blockIdx.z;
  int l0 = blockIdx.x * 64, d0 = blockIdx.y * 64;
  int tx = threadIdx.x & 63, ty = threadIdx.x >> 6;
#pragma unroll
  for (int j = 0; j < 16; ++j) {
    int l = ty + j * 4;
    s[l][tx] = qkv[(size_t)(b * LSEQ + l0 + l) * QKV_N + 2 * DIM + d0 + tx];
  }
  __syncthreads();
#pragma unroll
  for (int j = 0; j < 16; ++j) {
    int d = ty + j * 4;
    vT[((size_t)b * DIM + d0 + d) * LSEQ + l0 + tx] = s[tx][d];
  }
}

// row softmax: S (4096 fp16) -> P fp16
__global__ __launch_bounds__(256) void k_softmax(
    const half_t* __restrict__ S, half_t* __restrict__ P)
{
  int row = blockIdx.x;
  const half_t* srow = S + (size_t)row * LSEQ;
  int t = threadIdx.x;
  f16x8 hv[2];
  float vf[16];
  float mx = -1e30f;
#pragma unroll
  for (int i = 0; i < 2; ++i) {
    hv[i] = ((const f16x8*)srow)[t + 256 * i];
#pragma unroll
    for (int j = 0; j < 8; ++j) {
      vf[i * 8 + j] = (float)hv[i][j];
      mx = fmaxf(mx, vf[i * 8 + j]);
    }
  }
  for (int o = 32; o; o >>= 1) mx = fmaxf(mx, __shfl_xor(mx, o));
  __shared__ float rmx[4], rsum[4];
  int lane = t & 63, w = t >> 6;
  if (lane == 0) rmx[w] = mx;
  __syncthreads();
  mx = fmaxf(fmaxf(rmx[0], rmx[1]), fmaxf(rmx[2], rmx[3]));
  float s = 0.f;
#pragma unroll
  for (int i = 0; i < 16; ++i) {
    vf[i] = __expf(vf[i] - mx);
    s += vf[i];
  }
  for (int o = 32; o; o >>= 1) s += __shfl_xor(s, o);
  if (lane == 0) rsum[w] = s;
  __syncthreads();
  s = rsum[0] + rsum[1] + rsum[2] + rsum[3];
  float inv = 1.f / s;
#pragma unroll
  for (int i = 0; i < 2; ++i) {
    f16x8 ob;
#pragma unroll
    for (int j = 0; j < 8; ++j) ob[j] = (half_t)(vf[i * 8 + j] * inv);
    ((f16x8*)&P[(size_t)row * LSEQ])[t + 256 * i] = ob;
  }
}

extern "C" void kernel_launch(void* const* d_in, const int* in_sizes, int n_in,
                              void* d_out, int out_size, void* d_ws, size_t ws_size,
                              hipStream_t stream) {
  const float* hs      = (const float*)d_in[0];
  const float* temb    = (const float*)d_in[1];
  const float* rope    = (const float*)d_in[2];
  const float* w_lin   = (const float*)d_in[3];
  const float* b_lin   = (const float*)d_in[4];
  const float* w1      = (const float*)d_in[5];
  const float* b1      = (const float*)d_in[6];
  const float* w2      = (const float*)d_in[7];
  const float* b2      = (const float*)d_in[8];
  const float* q_scale = (const float*)d_in[9];
  const float* k_scale = (const float*)d_in[10];
  float* out = (float*)d_out;

  char* ws = (char*)d_ws;
  size_t off = 0;
  auto alloc = [&](size_t bytes) { char* p = ws + off; off += (bytes + 255) & ~(size_t)255; return p; };
  float*  emb    = (float*) alloc((size_t)BATCH * QKV_N * 4);
  half_t* xmod   = (half_t*)alloc((size_t)NROWS * DIM * 2);
  half_t* w1T    = (half_t*)alloc((size_t)N1 * DIM * 2);
  half_t* w2T    = (half_t*)alloc((size_t)DIM * CAT_N * 2);
  half_t* qkv    = (half_t*)alloc((size_t)NROWS * QKV_N * 2);
  half_t* concat = (half_t*)alloc((size_t)NROWS * CAT_N * 2);
  half_t* vT     = (half_t*)alloc((size_t)BATCH * DIM * LSEQ * 2);
  half_t* Sbuf   = (half_t*)alloc((size_t)LSEQ * LSEQ * 2);
  half_t* Pbuf   = (half_t*)alloc((size_t)LSEQ * LSEQ * 2);
  (void)ws_size; (void)n_in; (void)in_sizes; (void)out_size;

  k_emb<<<dim3(QKV_N / 256, BATCH), 256, 0, stream>>>(temb, w_lin, b_lin, emb);
  k_transpose_cvt<<<dim3(N1 / 64, DIM / 64), 256, 0, stream>>>(w1, w1T, DIM, N1);
  k_transpose_cvt<<<dim3(DIM / 64, CAT_N / 64), 256, 0, stream>>>(w2, w2T, CAT_N, DIM);
  k_lnmod<<<NROWS, 256, 0, stream>>>(hs, emb, xmod);

  // GEMM1: proj = xmod @ w1 + b1 ; qkv part -> qkv buf, mlp part -> gelu -> concat[:,3072:]
  EpiParams ep1 = {b1, nullptr, 0, qkv, QKV_N, concat, CAT_N, nullptr, nullptr, 0.f};
  gemm256<0><<<(N1 / 256) * (NROWS / 256), 512, 0, stream>>>(
      xmod, DIM, w1T, DIM, N1 / 256, NROWS / 256, QKV_N, DIM, ep1);

  k_qk_rmsrope<<<(NROWS * NH * 2) / 4, 256, 0, stream>>>(qkv, rope, q_scale, k_scale);
  k_vT<<<dim3(LSEQ / 64, DIM / 64, BATCH), 256, 0, stream>>>(qkv, vT);

  for (int b = 0; b < BATCH; ++b) {
    const half_t* qb = qkv + (size_t)b * LSEQ * QKV_N;
    EpiParams epS = {nullptr, nullptr, 0, Sbuf, LSEQ, nullptr, 0, nullptr, nullptr, 0.08838834764831845f};
    gemm256<1><<<(LSEQ / 256) * (LSEQ / 256), 512, 0, stream>>>(
        qb, QKV_N, qb + DIM, QKV_N, LSEQ / 256, LSEQ / 256, 0, DIM, epS);
    k_softmax<<<LSEQ, 256, 0, stream>>>(Sbuf, Pbuf);
    EpiParams epPV = {nullptr, nullptr, 0, nullptr, 0,
                      concat + (size_t)b * LSEQ * CAT_N, CAT_N, nullptr, nullptr, 0.f};
    gemm256<2><<<(DIM / 256) * (LSEQ / 256), 512, 0, stream>>>(
        Pbuf, LSEQ, vT + (size_t)b * DIM * LSEQ, LSEQ, DIM / 256, LSEQ / 256, 0, LSEQ, epPV);
  }

  // GEMM2: out = resid + gate * (concat @ w2 + b2)
  EpiParams ep2 = {b2, out, DIM, nullptr, 0, nullptr, 0, hs, emb + 2 * DIM, 0.f};
  gemm256<3><<<(DIM / 256) * (NROWS / 256), 512, 0, stream>>>(
      concat, CAT_N, w2T, CAT_N, DIM / 256, NROWS / 256, 0, CAT_N, ep2);
}

// Round 12
// 2788.390 us; speedup vs baseline: 1.5618x; 1.0036x over previous
//
#include <hip/hip_runtime.h>
#include <hip/hip_fp16.h>

typedef _Float16 half_t;
typedef __attribute__((ext_vector_type(8))) _Float16 f16x8;
typedef __attribute__((ext_vector_type(4))) float f32x4;

#define DIM   3072
#define NH    24
#define DH    128
#define MLP_D 12288
#define LSEQ  4096
#define BATCH 2
#define NROWS 8192           // B*L
#define N1    21504          // 3*DIM + MLP
#define QKV_N 9216           // 3*DIM
#define CAT_N 15360          // DIM + MLP

__device__ __forceinline__ void gload16(const void* g, void* l) {
  __builtin_amdgcn_global_load_lds((const __attribute__((address_space(1))) void*)g,
                                   (__attribute__((address_space(3))) void*)l, 16, 0, 0);
}

__device__ __forceinline__ float gelu_tanh(float x) {
  float u = 0.7978845608028654f * (x + 0.044715f * x * x * x);
  float t = 1.f - 2.f / (__expf(2.f * u) + 1.f);   // tanh(u)
  return 0.5f * x * (1.f + t);
}

struct EpiParams {
  const float* bias;
  float* outF; int ldoF;
  half_t* o1; int ldo1;   // qkv dest (EPI0) / S dest fp16 (EPI1)
  half_t* o2; int ldo2;   // concat dest (EPI0 gelu part, EPI2)
  const float* resid;
  const float* gate;      // emb+6144, stride 9216 per batch
  float scale;
};

// ============================================================================
// R6 phase skeleton, UNPINNED: no sched_barrier(0), no manual lgkmcnt asm in
// the hot loop. The compiler's own fine-grained partial lgkmcnt(N) waits
// (m97-verified) interleave MFMA with LDS read service — the overlap that the
// pinned variants (R5-R8, all ~44% MfmaUtil) structurally prevented.
// Correctness without the manual lgkm drains: every ds_read is consumed by a
// register-dependent MFMA BEFORE the STAGE that overwrites its region
// (program order), so compiler waits cover the RAW hazard; cross-tile
// reordering is fenced by the vmcnt asm's "memory" clobber.
// 256x256 tile, BK=64, 8 waves (2M x 4N), 2-deep LDS dbuf, counted vmcnt(6),
// setprio around MFMA clusters. XOR chunk swizzle (verified 0-conflict):
// phys = logical ^ ((row>>1)&3), inverse perm on the GLOBAL source (rule 21).
// EPI1 writes S as fp16.
// ============================================================================
template<int EPI>
__global__ __launch_bounds__(512, 2) void gemm256(
    const half_t* __restrict__ A, int lda,
    const half_t* __restrict__ B, int ldb,
    int nbx, int nby, int nsplit, int K, EpiParams ep)
{
  __shared__ __align__(16) char lds[131072];
  const int t = threadIdx.x, lane = t & 63, wid = t >> 6;

  // ---- block swizzle: XCD-contiguous chunks + 8-M-block supertile ----
  const int nwg = nbx * nby;
  const int wg = blockIdx.x;
  const int id = (wg & 7) * (nwg >> 3) + (wg >> 3);   // bijective (nwg%8==0)
  const int panel = 8 * nbx;
  const int bm = (id / panel) * 8 + (id % 8);
  const int bn = (id % panel) / 8;
  const int brow = bm * 256, bcol = bn * 256;
  const int wr = wid >> 2, wc = wid & 3;              // 2 x 4 waves

  f32x4 acc[8][4];
#pragma unroll
  for (int m = 0; m < 8; ++m)
#pragma unroll
    for (int n = 0; n < 4; ++n) acc[m][n] = (f32x4){0.f, 0.f, 0.f, 0.f};

  // ---- staging pointers: lane l -> row (l>>2)[+16], chunk (l&3); source
  // chunk inverse-permuted so LDS holds phys = logical ^ ((row>>1)&3)
  const int scol = (((lane & 3) ^ ((lane >> 3) & 3)) * 8);   // halves
  const half_t* pA = A + (size_t)(brow + wid * 32 + (lane >> 2)) * lda + scol;
  const half_t* pB = B + (size_t)(bcol + wid * 32 + (lane >> 2)) * ldb + scol;
  const int wrow = wid * 2048;          // byte offset of this wave's 32 rows
  const int NT = K >> 6;

  // ---- fragment read offsets (swizzled chunk) ----
  const int pc = (((lane >> 4) ^ ((lane >> 1) & 3)) << 4);   // bytes
  const int aoff = (wr * 128 + (lane & 15)) * 64 + pc;
  const int boff = 32768 + (wc * 64 + (lane & 15)) * 64 + pc;

  f16x8 af[2][4], bf[2][4];

#define STAGE_A(bb, kh, tk) {                                               \
    gload16(pA + (size_t)(tk) * 64 + (kh) * 32,                             \
            (bb) + (kh) * 16384 + wrow);                                    \
    gload16(pA + (size_t)(tk) * 64 + (kh) * 32 + (size_t)16 * lda,          \
            (bb) + (kh) * 16384 + wrow + 1024); }
#define STAGE_B(bb, kh, tk) {                                               \
    gload16(pB + (size_t)(tk) * 64 + (kh) * 32,                             \
            (bb) + 32768 + (kh) * 16384 + wrow);                            \
    gload16(pB + (size_t)(tk) * 64 + (kh) * 32 + (size_t)16 * ldb,          \
            (bb) + 32768 + (kh) * 16384 + wrow + 1024); }

#define MFMA_Q(accoff, ab, bb2)                                             \
    _Pragma("unroll")                                                       \
    for (int mi = 0; mi < 4; ++mi)                                          \
      _Pragma("unroll")                                                     \
      for (int nj = 0; nj < 4; ++nj)                                        \
        acc[(accoff) + mi][nj] = __builtin_amdgcn_mfma_f32_16x16x32_f16(    \
            af[ab][mi], bf[bb2][nj], acc[(accoff) + mi][nj], 0, 0, 0);

  // ---- prologue: stage tiles 0 and 1; pre-read Q0 fragments of tile 0 ----
  {
    char* b0 = lds;
    char* b1 = lds + 65536;
    STAGE_B(b0, 0, 0); STAGE_A(b0, 0, 0); STAGE_B(b0, 1, 0); STAGE_A(b0, 1, 0);
    STAGE_B(b1, 0, 1); STAGE_A(b1, 0, 1); STAGE_B(b1, 1, 1); STAGE_A(b1, 1, 1);
    asm volatile("s_waitcnt vmcnt(8)" ::: "memory");   // tile 0 landed
    __builtin_amdgcn_s_barrier();
#pragma unroll
    for (int mi = 0; mi < 4; ++mi) af[0][mi] = *(const f16x8*)(lds + aoff + mi * 1024);
#pragma unroll
    for (int nj = 0; nj < 4; ++nj) bf[0][nj] = *(const f16x8*)(lds + boff + nj * 1024);
    __builtin_amdgcn_s_barrier();      // all waves issued pre-reads
  }

  for (int tt = 0; tt < NT; ++tt) {
    char* cb = lds + (size_t)(tt & 1) * 65536;
    char* nb = lds + (size_t)((tt & 1) ^ 1) * 65536;

    // ===== P0: MFMA Q0 (kk0,mh0); read af[1] <- A kh0 mh1; stage B kh0 =====
    __builtin_amdgcn_s_setprio(1);
    MFMA_Q(0, 0, 0)
    __builtin_amdgcn_s_setprio(0);
#pragma unroll
    for (int mi = 0; mi < 4; ++mi) af[1][mi] = *(const f16x8*)(cb + aoff + 4096 + mi * 1024);
    if (tt + 2 < NT) STAGE_B(cb, 0, tt + 2);
    __builtin_amdgcn_s_barrier();

    // ===== P1: MFMA Q1 (kk0,mh1) w/ bf0; read af[0] <- A kh1 mh0, bf[1] <- B kh1;
    //           stage A kh0 =====
    __builtin_amdgcn_s_setprio(1);
    MFMA_Q(4, 1, 0)
    __builtin_amdgcn_s_setprio(0);
#pragma unroll
    for (int mi = 0; mi < 4; ++mi) af[0][mi] = *(const f16x8*)(cb + aoff + 16384 + mi * 1024);
#pragma unroll
    for (int nj = 0; nj < 4; ++nj) bf[1][nj] = *(const f16x8*)(cb + boff + 16384 + nj * 1024);
    if (tt + 2 < NT) STAGE_A(cb, 0, tt + 2);
    __builtin_amdgcn_s_barrier();

    // ===== P2: MFMA Q2 (kk1,mh0) w/ bf1; read af[1] <- A kh1 mh1; stage B kh1;
    //           vmcnt gate for next-buffer reads =====
    __builtin_amdgcn_s_setprio(1);
    MFMA_Q(0, 0, 1)
    __builtin_amdgcn_s_setprio(0);
#pragma unroll
    for (int mi = 0; mi < 4; ++mi) af[1][mi] = *(const f16x8*)(cb + aoff + 16384 + 4096 + mi * 1024);
    if (tt + 2 < NT) STAGE_B(cb, 1, tt + 2);
    if (tt + 2 < NT) asm volatile("s_waitcnt vmcnt(6)" ::: "memory");
    else             asm volatile("s_waitcnt vmcnt(0)" ::: "memory");
    __builtin_amdgcn_s_barrier();

    // ===== P3: MFMA Q3 (kk1,mh1) w/ bf1; read next tile's Q0 frags from nb;
    //           stage A kh1 =====
    __builtin_amdgcn_s_setprio(1);
    MFMA_Q(4, 1, 1)
    __builtin_amdgcn_s_setprio(0);
    if (tt + 1 < NT) {
#pragma unroll
      for (int mi = 0; mi < 4; ++mi) af[0][mi] = *(const f16x8*)(nb + aoff + mi * 1024);
#pragma unroll
      for (int nj = 0; nj < 4; ++nj) bf[0][nj] = *(const f16x8*)(nb + boff + nj * 1024);
    }
    if (tt + 2 < NT) STAGE_A(cb, 1, tt + 2);
    __builtin_amdgcn_s_barrier();
  }
#undef STAGE_A
#undef STAGE_B
#undef MFMA_Q

  // ---- epilogue ----
  const int laneR = lane & 15;
  const int colb = bcol + wc * 64;
  const int rowb = brow + wr * 128 + (lane >> 4) * 4;
#pragma unroll
  for (int mi = 0; mi < 8; ++mi) {
#pragma unroll
    for (int nj = 0; nj < 4; ++nj) {
      int col = colb + nj * 16 + laneR;
#pragma unroll
      for (int j = 0; j < 4; ++j) {
        int row = rowb + mi * 16 + j;
        float v = acc[mi][nj][j];
        if (EPI == 0) {
          v += ep.bias[col];
          if (col < nsplit) {
            ep.o1[(size_t)row * ep.ldo1 + col] = (half_t)v;
          } else {
            ep.o2[(size_t)row * ep.ldo2 + DIM + (col - nsplit)] = (half_t)gelu_tanh(v);
          }
        } else if (EPI == 1) {
          ep.o1[(size_t)row * ep.ldo1 + col] = (half_t)(v * ep.scale);
        } else if (EPI == 2) {
          ep.o2[(size_t)row * ep.ldo2 + col] = (half_t)v;
        } else {
          v += ep.bias[col];
          int b = row >> 12;
          float g = ep.gate[(size_t)b * QKV_N + col];
          float r = ep.resid[(size_t)row * DIM + col];
          ep.outF[(size_t)row * ep.ldoF + col] = r + g * v;
        }
      }
    }
  }
}

// emb = silu(temb) @ w_lin + b_lin   (2 x 9216)
__global__ __launch_bounds__(256) void k_emb(
    const float* __restrict__ temb, const float* __restrict__ w_lin,
    const float* __restrict__ b_lin, float* __restrict__ emb)
{
  __shared__ float s[DIM];
  int b = blockIdx.y;
  int col = blockIdx.x * 256 + threadIdx.x;
  const float* tr = temb + (size_t)b * DIM;
  for (int k = threadIdx.x; k < DIM; k += 256) {
    float x = tr[k];
    s[k] = x / (1.f + __expf(-x));
  }
  __syncthreads();
  float acc = b_lin[col];
  for (int k = 0; k < DIM; k += 4) {
    acc += s[k] * w_lin[(size_t)k * QKV_N + col]
         + s[k + 1] * w_lin[(size_t)(k + 1) * QKV_N + col]
         + s[k + 2] * w_lin[(size_t)(k + 2) * QKV_N + col]
         + s[k + 3] * w_lin[(size_t)(k + 3) * QKV_N + col];
  }
  emb[(size_t)b * QKV_N + col] = acc;
}

// LayerNorm + (1+scale)*xhat + shift -> fp16
__global__ __launch_bounds__(256) void k_lnmod(
    const float* __restrict__ hs, const float* __restrict__ emb,
    half_t* __restrict__ xmod)
{
  int row = blockIdx.x;
  int b = row >> 12;
  const float* x = hs + (size_t)row * DIM;
  int t = threadIdx.x;
  float s = 0.f, s2 = 0.f;
  float4 v[3];
#pragma unroll
  for (int i = 0; i < 3; ++i) {
    v[i] = ((const float4*)x)[t + 256 * i];
    s  += v[i].x + v[i].y + v[i].z + v[i].w;
    s2 += v[i].x * v[i].x + v[i].y * v[i].y + v[i].z * v[i].z + v[i].w * v[i].w;
  }
  for (int o = 32; o; o >>= 1) { s += __shfl_xor(s, o); s2 += __shfl_xor(s2, o); }
  __shared__ float rs[4], rs2[4];
  int lane = t & 63, w = t >> 6;
  if (lane == 0) { rs[w] = s; rs2[w] = s2; }
  __syncthreads();
  s = rs[0] + rs[1] + rs[2] + rs[3];
  s2 = rs2[0] + rs2[1] + rs2[2] + rs2[3];
  float mu = s * (1.f / DIM);
  float var = s2 * (1.f / DIM) - mu * mu;
  float rstd = rsqrtf(var + 1e-6f);
  const float* shift = emb + (size_t)b * QKV_N;
  const float* scale = shift + DIM;
#pragma unroll
  for (int i = 0; i < 3; ++i) {
    int g = t + 256 * i;
    float4 sc = ((const float4*)scale)[g];
    float4 sh = ((const float4*)shift)[g];
    half_t ob[4];
    float vv[4] = {v[i].x, v[i].y, v[i].z, v[i].w};
    float scv[4] = {sc.x, sc.y, sc.z, sc.w};
    float shv[4] = {sh.x, sh.y, sh.z, sh.w};
#pragma unroll
    for (int j = 0; j < 4; ++j) {
      float xn = (vv[j] - mu) * rstd;
      ob[j] = (half_t)(xn * (1.f + scv[j]) + shv[j]);
    }
    *(uint2*)&xmod[(size_t)row * DIM + g * 4] = *(uint2*)ob;
  }
}

// f32 (RxC) -> fp16 transposed (CxR)
__global__ __launch_bounds__(256) void k_transpose_cvt(
    const float* __restrict__ in, half_t* __restrict__ out, int R, int C)
{
  __shared__ float s[64][65];
  int c0 = blockIdx.x * 64, r0 = blockIdx.y * 64;
  int tx = threadIdx.x & 63, ty = threadIdx.x >> 6;
#pragma unroll
  for (int j = 0; j < 16; ++j) {
    int r = ty + j * 4;
    s[r][tx] = in[(size_t)(r0 + r) * C + c0 + tx];
  }
  __syncthreads();
#pragma unroll
  for (int j = 0; j < 16; ++j) {
    int c = ty + j * 4;
    out[(size_t)(c0 + c) * R + r0 + tx] = (half_t)s[tx][c];
  }
}

// RMS + RoPE on q,k in-place in qkv buffer. One wave per (row, head, q/k).
__global__ __launch_bounds__(256) void k_qk_rmsrope(
    half_t* __restrict__ qkv, const float* __restrict__ rope,
    const float* __restrict__ q_scale, const float* __restrict__ k_scale)
{
  int w = blockIdx.x * 4 + (threadIdx.x >> 6);
  int lane = threadIdx.x & 63;
  int qk = w & 1;
  int hr = w >> 1;               // bl*24 + h
  int h = hr % 24;
  int bl = hr / 24;              // b*4096 + l
  size_t base = (size_t)bl * QKV_N + qk * DIM + h * DH;
  float x0 = (float)qkv[base + lane * 2];
  float x1 = (float)qkv[base + lane * 2 + 1];
  float ss = x0 * x0 + x1 * x1;
  for (int o = 32; o; o >>= 1) ss += __shfl_xor(ss, o);
  float r = rsqrtf(ss * (1.f / DH) + 1e-6f);
  const float* sc = qk ? k_scale : q_scale;
  float xs0 = x0 * r * sc[lane * 2];
  float xs1 = x1 * r * sc[lane * 2 + 1];
  int l = bl & (LSEQ - 1);
  float4 fr = ((const float4*)rope)[(size_t)l * 64 + lane];
  qkv[base + lane * 2]     = (half_t)(fr.x * xs0 + fr.y * xs1);
  qkv[base + lane * 2 + 1] = (half_t)(fr.z * xs0 + fr.w * xs1);
}

// v part of qkv -> vT (per batch: DIM x LSEQ), tiled transpose
__global__ __launch_bounds__(256) void k_vT(
    const half_t* __restrict__ qkv, half_t* __restrict__ vT)
{
  __shared__ half_t s[64][65];
  int b = blockIdx.z;
  int l0 = blockIdx.x * 64, d0 = blockIdx.y * 64;
  int tx = threadIdx.x & 63, ty = threadIdx.x >> 6;
#pragma unroll
  for (int j = 0; j < 16; ++j) {
    int l = ty + j * 4;
    s[l][tx] = qkv[(size_t)(b * LSEQ + l0 + l) * QKV_N + 2 * DIM + d0 + tx];
  }
  __syncthreads();
#pragma unroll
  for (int j = 0; j < 16; ++j) {
    int d = ty + j * 4;
    vT[((size_t)b * DIM + d0 + d) * LSEQ + l0 + tx] = s[tx][d];
  }
}

// row softmax: S (4096 fp16) -> P fp16
__global__ __launch_bounds__(256) void k_softmax(
    const half_t* __restrict__ S, half_t* __restrict__ P)
{
  int row = blockIdx.x;
  const half_t* srow = S + (size_t)row * LSEQ;
  int t = threadIdx.x;
  f16x8 hv[2];
  float vf[16];
  float mx = -1e30f;
#pragma unroll
  for (int i = 0; i < 2; ++i) {
    hv[i] = ((const f16x8*)srow)[t + 256 * i];
#pragma unroll
    for (int j = 0; j < 8; ++j) {
      vf[i * 8 + j] = (float)hv[i][j];
      mx = fmaxf(mx, vf[i * 8 + j]);
    }
  }
  for (int o = 32; o; o >>= 1) mx = fmaxf(mx, __shfl_xor(mx, o));
  __shared__ float rmx[4], rsum[4];
  int lane = t & 63, w = t >> 6;
  if (lane == 0) rmx[w] = mx;
  __syncthreads();
  mx = fmaxf(fmaxf(rmx[0], rmx[1]), fmaxf(rmx[2], rmx[3]));
  float s = 0.f;
#pragma unroll
  for (int i = 0; i < 16; ++i) {
    vf[i] = __expf(vf[i] - mx);
    s += vf[i];
  }
  for (int o = 32; o; o >>= 1) s += __shfl_xor(s, o);
  if (lane == 0) rsum[w] = s;
  __syncthreads();
  s = rsum[0] + rsum[1] + rsum[2] + rsum[3];
  float inv = 1.f / s;
#pragma unroll
  for (int i = 0; i < 2; ++i) {
    f16x8 ob;
#pragma unroll
    for (int j = 0; j < 8; ++j) ob[j] = (half_t)(vf[i * 8 + j] * inv);
    ((f16x8*)&P[(size_t)row * LSEQ])[t + 256 * i] = ob;
  }
}

extern "C" void kernel_launch(void* const* d_in, const int* in_sizes, int n_in,
                              void* d_out, int out_size, void* d_ws, size_t ws_size,
                              hipStream_t stream) {
  const float* hs      = (const float*)d_in[0];
  const float* temb    = (const float*)d_in[1];
  const float* rope    = (const float*)d_in[2];
  const float* w_lin   = (const float*)d_in[3];
  const float* b_lin   = (const float*)d_in[4];
  const float* w1      = (const float*)d_in[5];
  const float* b1      = (const float*)d_in[6];
  const float* w2      = (const float*)d_in[7];
  const float* b2      = (const float*)d_in[8];
  const float* q_scale = (const float*)d_in[9];
  const float* k_scale = (const float*)d_in[10];
  float* out = (float*)d_out;

  char* ws = (char*)d_ws;
  size_t off = 0;
  auto alloc = [&](size_t bytes) { char* p = ws + off; off += (bytes + 255) & ~(size_t)255; return p; };
  float*  emb    = (float*) alloc((size_t)BATCH * QKV_N * 4);
  half_t* xmod   = (half_t*)alloc((size_t)NROWS * DIM * 2);
  half_t* w1T    = (half_t*)alloc((size_t)N1 * DIM * 2);
  half_t* w2T    = (half_t*)alloc((size_t)DIM * CAT_N * 2);
  half_t* qkv    = (half_t*)alloc((size_t)NROWS * QKV_N * 2);
  half_t* concat = (half_t*)alloc((size_t)NROWS * CAT_N * 2);
  half_t* vT     = (half_t*)alloc((size_t)BATCH * DIM * LSEQ * 2);
  half_t* Sbuf   = (half_t*)alloc((size_t)LSEQ * LSEQ * 2);
  half_t* Pbuf   = (half_t*)alloc((size_t)LSEQ * LSEQ * 2);
  (void)ws_size; (void)n_in; (void)in_sizes; (void)out_size;

  k_emb<<<dim3(QKV_N / 256, BATCH), 256, 0, stream>>>(temb, w_lin, b_lin, emb);
  k_transpose_cvt<<<dim3(N1 / 64, DIM / 64), 256, 0, stream>>>(w1, w1T, DIM, N1);
  k_transpose_cvt<<<dim3(DIM / 64, CAT_N / 64), 256, 0, stream>>>(w2, w2T, CAT_N, DIM);
  k_lnmod<<<NROWS, 256, 0, stream>>>(hs, emb, xmod);

  // GEMM1: proj = xmod @ w1 + b1 ; qkv part -> qkv buf, mlp part -> gelu -> concat[:,3072:]
  EpiParams ep1 = {b1, nullptr, 0, qkv, QKV_N, concat, CAT_N, nullptr, nullptr, 0.f};
  gemm256<0><<<(N1 / 256) * (NROWS / 256), 512, 0, stream>>>(
      xmod, DIM, w1T, DIM, N1 / 256, NROWS / 256, QKV_N, DIM, ep1);

  k_qk_rmsrope<<<(NROWS * NH * 2) / 4, 256, 0, stream>>>(qkv, rope, q_scale, k_scale);
  k_vT<<<dim3(LSEQ / 64, DIM / 64, BATCH), 256, 0, stream>>>(qkv, vT);

  for (int b = 0; b < BATCH; ++b) {
    const half_t* qb = qkv + (size_t)b * LSEQ * QKV_N;
    EpiParams epS = {nullptr, nullptr, 0, Sbuf, LSEQ, nullptr, 0, nullptr, nullptr, 0.08838834764831845f};
    gemm256<1><<<(LSEQ / 256) * (LSEQ / 256), 512, 0, stream>>>(
        qb, QKV_N, qb + DIM, QKV_N, LSEQ / 256, LSEQ / 256, 0, DIM, epS);
    k_softmax<<<LSEQ, 256, 0, stream>>>(Sbuf, Pbuf);
    EpiParams epPV = {nullptr, nullptr, 0, nullptr, 0,
                      concat + (size_t)b * LSEQ * CAT_N, CAT_N, nullptr, nullptr, 0.f};
    gemm256<2><<<(DIM / 256) * (LSEQ / 256), 512, 0, stream>>>(
        Pbuf, LSEQ, vT + (size_t)b * DIM * LSEQ, LSEQ, DIM / 256, LSEQ / 256, 0, LSEQ, epPV);
  }

  // GEMM2: out = resid + gate * (concat @ w2 + b2)
  EpiParams ep2 = {b2, out, DIM, nullptr, 0, nullptr, 0, hs, emb + 2 * DIM, 0.f};
  gemm256<3><<<(DIM / 256) * (NROWS / 256), 512, 0, stream>>>(
      concat, CAT_N, w2T, CAT_N, DIM / 256, NROWS / 256, 0, CAT_N, ep2);
}